// Round 6
// baseline (231.317 us; speedup 1.0000x reference)
//
#include <hip/hip_runtime.h>
#include <math.h>

#define DIM 1024

// Native clang vector type — __builtin_nontemporal_load/store require a
// scalar or native vector, not HIP_vector_type<float,4>.
typedef float vfloat4 __attribute__((ext_vector_type(4)));

// R6: LOOP-FREE exact-cover launch. 32768 blocks x 256 threads = n4
// threads; each thread handles exactly one float4. Mechanism under test:
//  - blocks dispatch roughly in order -> device walks x linearly
//    front-to-back (HBM row/bank locality) instead of 16 interleaved
//    8MB-strided sweeps;
//  - the single x-load is independent of the softmax prologue, so it
//    issues in the wave's first cycles and the whole prologue runs inside
//    its ~900cy latency shadow; no loop-carried anything.
// Thread t's float4 index is gid = blockIdx*256 + t, so its channel
// float4 is gid & 255 == t — the wave-redundant prologue already
// produces exactly the needed mask value.
//
// Ledger: NT/NT=226.1 best (NT/reg=229.6, reg/NT=237.6: allocating loads
// throttle issue, FETCH showed L3 serving half of x yet slower). R1
// distant 4x unroll -6.4us; R2 barrier-free prologue null; R5 1-deep
// prefetch null. Headline = kernel(~66us) + ~160us harness poison fills.
__global__ __launch_bounds__(256) void fused_mask_mul_kernel(
    const vfloat4* __restrict__ x,
    const vfloat4* __restrict__ mask_param4,  // 256 float4 = 1024 floats
    const vfloat4* __restrict__ mask_in4,     // 256 float4
    vfloat4* __restrict__ out,
    vfloat4* __restrict__ mask_out4,          // 256 float4 (output 1)
    int n4)
{
    const int t   = threadIdx.x;             // 0..255
    const int gid = blockIdx.x * 256 + t;    // one float4 per thread

    // Issue the streaming load FIRST — everything below is independent
    // and executes inside its latency shadow.
    vfloat4 xv;
    if (gid < n4) xv = __builtin_nontemporal_load(&x[gid]);

    const int l = t & 63;                    // lane
    const int w = t >> 6;                    // wave id in block

    // ---- wave-redundant softmax over 1024 channels, shuffle-only ----
    // Each lane reads 4 float4 columns: l, l+64, l+128, l+192 (L1-hot).
    const vfloat4 q0 = mask_param4[l];
    const vfloat4 q1 = mask_param4[l + 64];
    const vfloat4 q2 = mask_param4[l + 128];
    const vfloat4 q3 = mask_param4[l + 192];

    float m = fmaxf(fmaxf(q0.x, q0.y), fmaxf(q0.z, q0.w));
    m = fmaxf(m, fmaxf(fmaxf(q1.x, q1.y), fmaxf(q1.z, q1.w)));
    m = fmaxf(m, fmaxf(fmaxf(q2.x, q2.y), fmaxf(q2.z, q2.w)));
    m = fmaxf(m, fmaxf(fmaxf(q3.x, q3.y), fmaxf(q3.z, q3.w)));
    #pragma unroll
    for (int o = 32; o > 0; o >>= 1) m = fmaxf(m, __shfl_xor(m, o, 64));

    vfloat4 e0, e1, e2, e3;
    e0.x = __expf(q0.x - m); e0.y = __expf(q0.y - m);
    e0.z = __expf(q0.z - m); e0.w = __expf(q0.w - m);
    e1.x = __expf(q1.x - m); e1.y = __expf(q1.y - m);
    e1.z = __expf(q1.z - m); e1.w = __expf(q1.w - m);
    e2.x = __expf(q2.x - m); e2.y = __expf(q2.y - m);
    e2.z = __expf(q2.z - m); e2.w = __expf(q2.w - m);
    e3.x = __expf(q3.x - m); e3.y = __expf(q3.y - m);
    e3.z = __expf(q3.z - m); e3.w = __expf(q3.w - m);

    float s = (e0.x + e0.y + e0.z + e0.w) + (e1.x + e1.y + e1.z + e1.w)
            + (e2.x + e2.y + e2.z + e2.w) + (e3.x + e3.y + e3.z + e3.w);
    #pragma unroll
    for (int o = 32; o > 0; o >>= 1) s += __shfl_xor(s, o, 64);

    const float scale = (float)DIM / s;      // PRUNE_RATE = 1.0

    // Thread t's channels (4t..4t+3) are column t = l + 64*w -> e{w}.
    vfloat4 esel = (w == 0) ? e0 : (w == 1) ? e1 : (w == 2) ? e2 : e3;
    const vfloat4 mi = mask_in4[t];
    vfloat4 mv = esel * scale * mi;

    if (blockIdx.x == 0) mask_out4[t] = mv;

    if (gid < n4) {
        vfloat4 v = xv * mv;
        __builtin_nontemporal_store(v, &out[gid]);
    }
}

extern "C" void kernel_launch(void* const* d_in, const int* in_sizes, int n_in,
                              void* d_out, int out_size, void* d_ws, size_t ws_size,
                              hipStream_t stream)
{
    const float* x          = (const float*)d_in[0];   // [8,4096,1024] fp32
    const float* mask_param = (const float*)d_in[1];   // [1024] fp32
    const float* mask_in    = (const float*)d_in[2];   // [1024] fp32 (ones)

    const int n = in_sizes[0];                         // 33554432
    float* out_xm   = (float*)d_out;                   // output 0
    float* out_mask = (float*)d_out + n;               // output 1 (1024 floats)

    const int n4 = n / 4;                              // 8388608
    const int blocks = (n4 + 255) / 256;               // 32768: exact cover
    fused_mask_mul_kernel<<<blocks, 256, 0, stream>>>(
        (const vfloat4*)x, (const vfloat4*)mask_param, (const vfloat4*)mask_in,
        (vfloat4*)out_xm, (vfloat4*)out_mask, n4);
}

// Round 7
// 225.320 us; speedup vs baseline: 1.0266x; 1.0266x over previous
//
#include <hip/hip_runtime.h>
#include <math.h>

#define DIM 1024

// Native clang vector type — __builtin_nontemporal_load/store require a
// scalar or native vector, not HIP_vector_type<float,4>.
typedef float vfloat4 __attribute__((ext_vector_type(4)));

// R7: ADJACENT x2 unroll. Each block processes 512 consecutive float4
// (8 KB contiguous) per trip: thread t handles i and i+256. Each wave
// issues two back-to-back coalesced 1KB chunks, adjacent in HBM.
// Mechanism: MLP=2 per wave WITHOUT the distant-address pattern that
// killed R1 (its 4 loads were 8MB apart -> HBM page/bank thrash at the
// controllers; R1 had zero tail iterations, so the regression was the
// address pattern itself). Same grid (2048 blocks, 32 waves/CU), NT/NT.
// Mask invariance: i == t (mod 256) for both accesses.
//
// Ledger vs NT/NT grid-stride 226.1: R1 distant-4x +6.4; R2 prologue
// null; R3 reg-store +3.5; R4 reg-load +11.5 (L2 thrash, NOT BW-bound);
// R5 1-deep prefetch null; R6 loop-free +5.2. Headline = kernel(~66us)
// + ~160us harness poison fills. Pre-commit: null here -> ROOFLINE.
__global__ __launch_bounds__(256) void fused_mask_mul_kernel(
    const vfloat4* __restrict__ x,
    const vfloat4* __restrict__ mask_param4,  // 256 float4 = 1024 floats
    const vfloat4* __restrict__ mask_in4,     // 256 float4
    vfloat4* __restrict__ out,
    vfloat4* __restrict__ mask_out4,          // 256 float4 (output 1)
    int n4)
{
    const int t = threadIdx.x;               // 0..255
    const int l = t & 63;                    // lane
    const int w = t >> 6;                    // wave id in block

    // ---- wave-redundant softmax over 1024 channels, shuffle-only ----
    // Each lane reads 4 float4 columns: l, l+64, l+128, l+192.
    const vfloat4 q0 = mask_param4[l];
    const vfloat4 q1 = mask_param4[l + 64];
    const vfloat4 q2 = mask_param4[l + 128];
    const vfloat4 q3 = mask_param4[l + 192];

    float m = fmaxf(fmaxf(q0.x, q0.y), fmaxf(q0.z, q0.w));
    m = fmaxf(m, fmaxf(fmaxf(q1.x, q1.y), fmaxf(q1.z, q1.w)));
    m = fmaxf(m, fmaxf(fmaxf(q2.x, q2.y), fmaxf(q2.z, q2.w)));
    m = fmaxf(m, fmaxf(fmaxf(q3.x, q3.y), fmaxf(q3.z, q3.w)));
    #pragma unroll
    for (int o = 32; o > 0; o >>= 1) m = fmaxf(m, __shfl_xor(m, o, 64));

    vfloat4 e0, e1, e2, e3;
    e0.x = __expf(q0.x - m); e0.y = __expf(q0.y - m);
    e0.z = __expf(q0.z - m); e0.w = __expf(q0.w - m);
    e1.x = __expf(q1.x - m); e1.y = __expf(q1.y - m);
    e1.z = __expf(q1.z - m); e1.w = __expf(q1.w - m);
    e2.x = __expf(q2.x - m); e2.y = __expf(q2.y - m);
    e2.z = __expf(q2.z - m); e2.w = __expf(q2.w - m);
    e3.x = __expf(q3.x - m); e3.y = __expf(q3.y - m);
    e3.z = __expf(q3.z - m); e3.w = __expf(q3.w - m);

    float s = (e0.x + e0.y + e0.z + e0.w) + (e1.x + e1.y + e1.z + e1.w)
            + (e2.x + e2.y + e2.z + e2.w) + (e3.x + e3.y + e3.z + e3.w);
    #pragma unroll
    for (int o = 32; o > 0; o >>= 1) s += __shfl_xor(s, o, 64);

    const float scale = (float)DIM / s;      // PRUNE_RATE = 1.0

    // Thread t's own channels (4t..4t+3) are column t = l + 64*w -> e{w}.
    vfloat4 esel = (w == 0) ? e0 : (w == 1) ? e1 : (w == 2) ? e2 : e3;
    const vfloat4 mi = mask_in4[t];
    vfloat4 mv = esel * scale * mi;

    if (blockIdx.x == 0) mask_out4[t] = mv;

    // ---- adjacent x2 streaming: block owns 8KB contiguous per trip ----
    const int base   = blockIdx.x * 512 + t;
    const int stride = gridDim.x * 512;      // 2048*512 = 1,048,576
    int i = base;
    for (; i + 256 < n4; i += stride) {
        vfloat4 a = __builtin_nontemporal_load(&x[i]);
        vfloat4 b = __builtin_nontemporal_load(&x[i + 256]);
        a *= mv;
        b *= mv;
        __builtin_nontemporal_store(a, &out[i]);
        __builtin_nontemporal_store(b, &out[i + 256]);
    }
    // safety tail (not executed for the bench shape: exact cover)
    for (; i < n4; i += stride) {
        vfloat4 a = __builtin_nontemporal_load(&x[i]);
        a *= mv;
        __builtin_nontemporal_store(a, &out[i]);
    }
}

extern "C" void kernel_launch(void* const* d_in, const int* in_sizes, int n_in,
                              void* d_out, int out_size, void* d_ws, size_t ws_size,
                              hipStream_t stream)
{
    const float* x          = (const float*)d_in[0];   // [8,4096,1024] fp32
    const float* mask_param = (const float*)d_in[1];   // [1024] fp32
    const float* mask_in    = (const float*)d_in[2];   // [1024] fp32 (ones)

    const int n = in_sizes[0];                         // 33554432
    float* out_xm   = (float*)d_out;                   // output 0
    float* out_mask = (float*)d_out + n;               // output 1 (1024 floats)

    const int n4 = n / 4;                              // 8388608
    const int blocks = 2048;                           // 32 waves/CU
    fused_mask_mul_kernel<<<blocks, 256, 0, stream>>>(
        (const vfloat4*)x, (const vfloat4*)mask_param, (const vfloat4*)mask_in,
        (vfloat4*)out_xm, (vfloat4*)out_mask, n4);
}